// Round 1
// baseline (1189.208 us; speedup 1.0000x reference)
//
#include <hip/hip_runtime.h>

#define H 128
#define NG 384  // 3*H

typedef __bf16  bf16x8 __attribute__((ext_vector_type(8)));
typedef float   f32x4  __attribute__((ext_vector_type(4)));

__device__ inline unsigned short f2bf(float f) {
  unsigned int u = __float_as_uint(f);
  return (unsigned short)((u + 0x7FFFu + ((u >> 16) & 1u)) >> 16);
}

// Pass 1: last-occurrence-wins resolution (numpy scatter semantics).
__global__ void winner_kernel(const int* __restrict__ node_ids,
                              int* __restrict__ winner, int B) {
  int b = blockIdx.x * blockDim.x + threadIdx.x;
  if (b < B) atomicMax(&winner[node_ids[b]], b);
}

// Convert W_ih / W_hh to bf16 in workspace (row-major [384][128]).
__global__ void convw_kernel(const float* __restrict__ Wih,
                             const float* __restrict__ Whh,
                             unsigned short* __restrict__ Wb) {
  int i = blockIdx.x * blockDim.x + threadIdx.x;
  if (i < NG * H) Wb[i] = f2bf(Wih[i]);
  else if (i < 2 * NG * H) Wb[i] = f2bf(Whh[i - NG * H]);
}

// Copy memory -> out for rows NOT updated (winner < 0). Updated rows are
// written entirely by gru_kernel, so skipping them saves HBM traffic.
__global__ void copy_kernel(const float4* __restrict__ src,
                            float4* __restrict__ dst,
                            const int* __restrict__ winner, long long n4) {
  long long i = (long long)blockIdx.x * blockDim.x + threadIdx.x;
  if (i < n4) {
    int row = (int)(i >> 5);  // 32 float4 per 128-float row
    if (winner[row] < 0) dst[i] = src[i];
  }
}

// GRU: 64 batch rows per 256-thread block (4 waves x 16 rows).
// gi = x @ W_ih^T, gh = h @ W_hh^T via mfma_f32_16x16x32_bf16.
// A-frag: lane L elem j -> A[L&15][(L>>4)*8+j]
// B-frag: lane L elem j -> B[(L>>4)*8+j][L&15] = W[n0+(L&15)][k] (contiguous)
// C/D   : lane L reg  r -> D[(L>>4)*4+r][L&15]
__global__ void __launch_bounds__(256) gru_kernel(
    const int* __restrict__ node_ids, const float* __restrict__ messages,
    const float* __restrict__ memory, const float* __restrict__ b_ih,
    const float* __restrict__ b_hh, const unsigned short* __restrict__ Wb,
    const int* __restrict__ winner, float* __restrict__ out, int B) {

  __shared__ unsigned short x_bf[64 * 136];  // stride 136: 16B-aligned rows, 2-way banks
  __shared__ unsigned short h_bf[64 * 136];
  __shared__ float h_f32[64 * 132];          // f32 h for the z*h blend
  __shared__ float bi[NG], bh[NG];
  __shared__ int rows_node[64];
  __shared__ int rows_win[64];

  const int tid = threadIdx.x;
  const int base = blockIdx.x * 64;

  if (tid < 64) {
    int b = base + tid;
    int node = (b < B) ? node_ids[b] : 0;
    rows_node[tid] = node;
    rows_win[tid] = (b < B && winner[node] == b) ? 1 : 0;
  }
  for (int i = tid; i < NG; i += 256) { bi[i] = b_ih[i]; bh[i] = b_hh[i]; }
  __syncthreads();

  // Stage x and h tiles (64 rows x 128 cols) as bf16; h also as f32.
  for (int e = tid; e < 64 * 32; e += 256) {
    int r = e >> 5, c = e & 31;
    float4 xv = make_float4(0.f, 0.f, 0.f, 0.f);
    float4 hv = make_float4(0.f, 0.f, 0.f, 0.f);
    if (base + r < B) {
      xv = ((const float4*)messages)[(long long)(base + r) * 32 + c];
      hv = ((const float4*)memory)[(long long)rows_node[r] * 32 + c];
    }
    int k = c * 4;
    unsigned short* xp = x_bf + r * 136 + k;
    xp[0] = f2bf(xv.x); xp[1] = f2bf(xv.y); xp[2] = f2bf(xv.z); xp[3] = f2bf(xv.w);
    unsigned short* hp = h_bf + r * 136 + k;
    hp[0] = f2bf(hv.x); hp[1] = f2bf(hv.y); hp[2] = f2bf(hv.z); hp[3] = f2bf(hv.w);
    float* fp = h_f32 + r * 132 + k;
    fp[0] = hv.x; fp[1] = hv.y; fp[2] = hv.z; fp[3] = hv.w;
  }
  __syncthreads();

  const int lane = tid & 63;
  const int w = tid >> 6;
  const int lm = lane & 15;   // m (A) / n (B) / col (D) within tile
  const int q  = lane >> 4;   // quad
  const int m0 = w * 16;      // wave's batch-row base within block

  const unsigned short* wi = Wb;
  const unsigned short* wh = Wb + NG * H;

  for (int jg = 0; jg < 8; ++jg) {
    const int n0 = jg * 16;
    f32x4 air = {0.f,0.f,0.f,0.f}, aiz = air, ain = air;
    f32x4 ahr = air, ahz = air, ahn = air;

    for (int k0 = 0; k0 < H; k0 += 32) {
      const int ko = k0 + q * 8;
      bf16x8 ax = *(const bf16x8*)(x_bf + (m0 + lm) * 136 + ko);
      bf16x8 ah = *(const bf16x8*)(h_bf + (m0 + lm) * 136 + ko);
      bf16x8 br = *(const bf16x8*)(wi + (n0 + lm) * H + ko);
      bf16x8 bz = *(const bf16x8*)(wi + (128 + n0 + lm) * H + ko);
      bf16x8 bn = *(const bf16x8*)(wi + (256 + n0 + lm) * H + ko);
      bf16x8 cr = *(const bf16x8*)(wh + (n0 + lm) * H + ko);
      bf16x8 cz = *(const bf16x8*)(wh + (128 + n0 + lm) * H + ko);
      bf16x8 cn = *(const bf16x8*)(wh + (256 + n0 + lm) * H + ko);
      air = __builtin_amdgcn_mfma_f32_16x16x32_bf16(ax, br, air, 0, 0, 0);
      aiz = __builtin_amdgcn_mfma_f32_16x16x32_bf16(ax, bz, aiz, 0, 0, 0);
      ain = __builtin_amdgcn_mfma_f32_16x16x32_bf16(ax, bn, ain, 0, 0, 0);
      ahr = __builtin_amdgcn_mfma_f32_16x16x32_bf16(ah, cr, ahr, 0, 0, 0);
      ahz = __builtin_amdgcn_mfma_f32_16x16x32_bf16(ah, cz, ahz, 0, 0, 0);
      ahn = __builtin_amdgcn_mfma_f32_16x16x32_bf16(ah, cn, ahn, 0, 0, 0);
    }

    const int j = n0 + lm;  // col within [0,128)
    const float bir = bi[j], biz = bi[128 + j], bin = bi[256 + j];
    const float bhr = bh[j], bhz = bh[128 + j], bhn = bh[256 + j];

    #pragma unroll
    for (int r4 = 0; r4 < 4; ++r4) {
      const int m = m0 + q * 4 + r4;
      if (!rows_win[m]) continue;
      float ir = air[r4] + bir, hr = ahr[r4] + bhr;
      float iz = aiz[r4] + biz, hz = ahz[r4] + bhz;
      float in_ = ain[r4] + bin, hn = ahn[r4] + bhn;
      float rg = 1.f / (1.f + __expf(-(ir + hr)));
      float zg = 1.f / (1.f + __expf(-(iz + hz)));
      float t = in_ + rg * hn;
      t = fminf(fmaxf(t, -20.f), 20.f);
      float e2 = __expf(-2.f * t);
      float ng = (1.f - e2) / (1.f + e2);  // tanh(t)
      float hold = h_f32[m * 132 + j];
      float hnew = (1.f - zg) * ng + zg * hold;
      out[(long long)rows_node[m] * H + j] = hnew;
    }
  }
}

extern "C" void kernel_launch(void* const* d_in, const int* in_sizes, int n_in,
                              void* d_out, int out_size, void* d_ws, size_t ws_size,
                              hipStream_t stream) {
  const int* node_ids = (const int*)d_in[0];
  const float* messages = (const float*)d_in[1];
  const float* memory = (const float*)d_in[2];
  const float* W_ih = (const float*)d_in[3];
  const float* W_hh = (const float*)d_in[4];
  const float* b_ih = (const float*)d_in[5];
  const float* b_hh = (const float*)d_in[6];
  float* out = (float*)d_out;

  const int B = in_sizes[0];
  const int N = in_sizes[2] / H;  // num nodes

  // ws layout: winner int32[N] (4 MB), then W_ih|W_hh as bf16 (384 KB)
  int* winner = (int*)d_ws;
  unsigned short* Wb = (unsigned short*)((char*)d_ws + (size_t)N * 4);

  hipMemsetAsync(winner, 0xFF, (size_t)N * 4, stream);  // all -1
  winner_kernel<<<(B + 255) / 256, 256, 0, stream>>>(node_ids, winner, B);
  convw_kernel<<<(2 * NG * H + 255) / 256, 256, 0, stream>>>(W_ih, W_hh, Wb);

  long long n4 = (long long)N * (H / 4);
  copy_kernel<<<(int)((n4 + 255) / 256), 256, 0, stream>>>(
      (const float4*)memory, (float4*)out, winner, n4);

  gru_kernel<<<(B + 63) / 64, 256, 0, stream>>>(
      node_ids, messages, memory, b_ih, b_hh, Wb, winner, out, B);
}